// Round 17
// baseline (637.317 us; speedup 1.0000x reference)
//
#include <hip/hip_runtime.h>
#include <utility>

// Problem constants: N=262144 rows, NX=NQ=64, NU=16, fp32.
#define NROWS 262144
#define BT 512                 // threads/block (8 waves)
#define RPB 256                // rows/block (= 64 octets * 4 rows each)

typedef float f8v __attribute__((ext_vector_type(8)));
typedef float f2v __attribute__((ext_vector_type(2)));

// d_ws layout (floats) — two contiguous 9280-float phase blocks:
//  phase1 @0    : C1T[4096] | D11T[4096] | D12T[1024] | bv[64]
//  phase2 @9280 : AT [4096] | B1T [4096] | B2T [1024] | bx[64]
//  C1T[j*64+i]=C1[i][j]  D11T[i*64+k]=D11[k][i] (zeros at k<=i come from input)
//  D12T[j*64+i]=D12[i][j]  AT[j*64+k]=A[k][j]  B1T[i*64+k]=B1[k][i]
//  B2T[j*64+k]=B2[k][j]
// Fused kernel stages ONE 37.12 KB phase block at a time (overlay).
//
// R=4 octet geometry (verified correct in r11 at 56 VGPR): per wave-step the
// matrix chunk is 2 KB (vs 4 KB at R=2) -> LDS floor ~62us (r10 sits at 131,
// 94% of its 123us R=2 floor). r11 lost by broadcasting on the DS pipe; r12
// lost to tied-register partial-write DPP. This round: octet broadcast from
// THREE FULL-WRITE VALU ops (quad_perm bcast -> row_half_mirror -> cndmask
// vs a hoisted quad-parity mask) — no DS traffic, no tied registers.

__global__ void prep_kernel(const float* __restrict__ A, const float* __restrict__ B1,
                            const float* __restrict__ B2, const float* __restrict__ C1,
                            const float* __restrict__ D11, const float* __restrict__ D12,
                            const float* __restrict__ bv, const float* __restrict__ bx,
                            float* __restrict__ ws) {
    int g = blockIdx.x * 256 + threadIdx.x;
    if (g < 4096) {
        int r = g >> 6, c = g & 63;       // source row r, col c (64x64 row-major)
        int to = c * 64 + r;
        ws[0     + to] = C1[g];           // C1T
        ws[4096  + to] = D11[g];          // D11T
        ws[9280  + to] = A[g];            // AT
        ws[13376 + to] = B1[g];           // B1T
    }
    if (g < 1024) {
        int r = g >> 4, c = g & 15;       // 64x16 row-major source
        int to = c * 64 + r;
        ws[8192  + to] = D12[g];          // D12T
        ws[17472 + to] = B2[g];           // B2T
    }
    if (g < 64) {
        ws[9216  + g] = bv[g];
        ws[18496 + g] = bx[g];
    }
}

__device__ __forceinline__ f8v lds8(const float* p) { return *(const f8v*)p; }

// Pin pass boundaries (r6: +70 us): stops cross-pass live-range extension.
__device__ __forceinline__ void fence_sched() { __builtin_amdgcn_sched_barrier(0); }

// Octet (8-lane) broadcast from owner lane O, pure VALU, full-write only:
//  t1 = quad_perm[q,q,q,q] (q=O&3): each quad holds its own elem q.
//  t2 = row_half_mirror(t1): lane i <-> lane 7-i within each 8-lane half —
//       every lane sees the OTHER quad (of its octet)'s broadcast value.
//  result = (my quad parity == owner quad parity) ? t1 : t2  — cndmask on a
//       loop-invariant mask (selT1 computed once from tid, compare hoists).
template<int O>
__device__ __forceinline__ float obcast(float v, bool selT1) {
    const int t1 = __builtin_amdgcn_update_dpp(0, __float_as_int(v),
                                               (O & 3) * 0x55, 0xF, 0xF, true);
    const int t2 = __builtin_amdgcn_update_dpp(0, t1,
                                               0x141 /*row_half_mirror*/,
                                               0xF, 0xF, true);
    return __int_as_float(selT1 ? t1 : t2);
}

// Substitution step I, 4 rows sharing the D11T column chunk. Deferred-relu
// form (validated r14): s holds PRE-activation throughout; broadcast s[I],
// relu on the fly for the multiplier, no owner-finalize (D11T[I][I]==0
// keeps the owner's element untouched; zeros at k<I make those no-ops).
template<int I>
__device__ __forceinline__ void substep4(f8v& s0, f8v& s1, f8v& s2, f8v& s3,
                                         const float* D11s, int c8,
                                         bool inLow, bool inHigh) {
    const bool sel = ((I >> 3) < 4) ? inLow : inHigh;
    const float w0 = fmaxf(obcast<(I >> 3)>(s0[I & 7], sel), 0.0f);
    const float w1 = fmaxf(obcast<(I >> 3)>(s1[I & 7], sel), 0.0f);
    const float w2 = fmaxf(obcast<(I >> 3)>(s2[I & 7], sel), 0.0f);
    const float w3 = fmaxf(obcast<(I >> 3)>(s3[I & 7], sel), 0.0f);
    const f8v m = lds8(D11s + I * 64 + c8);
    s0 += m * w0;  s1 += m * w1;  s2 += m * w2;  s3 += m * w3;
}
template<int... Is>
__device__ __forceinline__ void subst_all4(f8v& s0, f8v& s1, f8v& s2, f8v& s3,
                                           const float* D11s, int c8,
                                           bool inLow, bool inHigh,
                                           std::integer_sequence<int, Is...>) {
    (substep4<Is>(s0, s1, s2, s3, D11s, c8, inLow, inHigh), ...);
}

// Deferred relu on one 8-wide fragment.
__device__ __forceinline__ void relu8(f8v& a) {
#pragma unroll
    for (int e = 0; e < 8; e++) a[e] = fmaxf(a[e], 0.0f);
}

// 64-dim matvec, 4 rows: one 32B matrix chunk (2 ds_read) feeds 32 FMAs;
// multiplier scalar for row r broadcast from octet lane J>>3, elem J&7.
template<int J>
__device__ __forceinline__ void mv64step4(f8v& a0, f8v& a1, f8v& a2, f8v& a3,
                                          const float* Ms, int c8,
                                          const f8v& f0, const f8v& f1,
                                          const f8v& f2, const f8v& f3,
                                          bool inLow, bool inHigh) {
    const bool sel = ((J >> 3) < 4) ? inLow : inHigh;
    const f8v m = lds8(Ms + J * 64 + c8);
    a0 += m * obcast<(J >> 3)>(f0[J & 7], sel);
    a1 += m * obcast<(J >> 3)>(f1[J & 7], sel);
    a2 += m * obcast<(J >> 3)>(f2[J & 7], sel);
    a3 += m * obcast<(J >> 3)>(f3[J & 7], sel);
}
template<int... Js>
__device__ __forceinline__ void mv64_4(f8v& a0, f8v& a1, f8v& a2, f8v& a3,
                                       const float* Ms, int c8,
                                       const f8v& f0, const f8v& f1,
                                       const f8v& f2, const f8v& f3,
                                       bool inLow, bool inHigh,
                                       std::integer_sequence<int, Js...>) {
    (mv64step4<Js>(a0, a1, a2, a3, Ms, c8, f0, f1, f2, f3, inLow, inHigh), ...);
}

// 16-dim matvec, 4 rows (u fragments: 2 floats/lane/row; owner lane J>>1).
template<int J>
__device__ __forceinline__ void mv16step4(f8v& a0, f8v& a1, f8v& a2, f8v& a3,
                                          const float* Ms, int c8,
                                          const f2v& f0, const f2v& f1,
                                          const f2v& f2, const f2v& f3,
                                          bool inLow, bool inHigh) {
    const bool sel = ((J >> 1) < 4) ? inLow : inHigh;
    const f8v m = lds8(Ms + J * 64 + c8);
    a0 += m * obcast<(J >> 1)>(f0[J & 1], sel);
    a1 += m * obcast<(J >> 1)>(f1[J & 1], sel);
    a2 += m * obcast<(J >> 1)>(f2[J & 1], sel);
    a3 += m * obcast<(J >> 1)>(f3[J & 1], sel);
}
template<int... Js>
__device__ __forceinline__ void mv16_4(f8v& a0, f8v& a1, f8v& a2, f8v& a3,
                                       const float* Ms, int c8,
                                       const f2v& f0, const f2v& f1,
                                       const f2v& f2, const f2v& f3,
                                       bool inLow, bool inHigh,
                                       std::integer_sequence<int, Js...>) {
    (mv16step4<Js>(a0, a1, a2, a3, Ms, c8, f0, f1, f2, f3, inLow, inHigh), ...);
}

// Fused kernel: octet (8 lanes) per FOUR rows (oct, oct+64, oct+128,
// oct+192); each lane owns an 8-output chunk per row. Overlay staging
// (37.12 KB). Pass order = r7/r10 register discipline:
//   stage p1; 1. s = bv + C1 x + D12 u  [xf, uf die]
//   2. substitution (pre-act) ; deferred relu -> w
//   overlay p2 (live: s only)
//   3. acc = bx + B1 w                  [s dies]
//   4. reload x,u; acc += Ax + B2u
// launch_bounds arg=3 (cap ~85 per measured model): r11's identical
// register shape compiled at 56 VGPR under this bound.
__global__ __launch_bounds__(BT, 3) void renl2_fused(const float* __restrict__ x,
                                                     const float* __restrict__ u,
                                                     const float* __restrict__ ws,
                                                     float* __restrict__ out) {
    __shared__ __align__(64) float sm[9280];    // 37.12 KB
    const int tid = threadIdx.x;
    const int c   = tid & 7;              // lane within octet
    const int c8  = c << 3;               // 8-float chunk offset
    const int oct = tid >> 3;             // octet id = base row within block
    const bool inLow  = ((tid >> 2) & 1) == 0;  // my quad parity within octet
    const bool inHigh = !inLow;
    const size_t row0 = (size_t)blockIdx.x * RPB;   // rows [row0, row0+256)

    // ---- per-lane x/u fragments, 4 rows each (fully coalesced) ----
    const float* xb = x + (row0 + oct) * 64 + c8;
    const float* ub = u + (row0 + oct) * 16 + (c << 1);
    const f8v xf0 = *(const f8v*)(xb);
    const f8v xf1 = *(const f8v*)(xb + 64 * 64);
    const f8v xf2 = *(const f8v*)(xb + 128 * 64);
    const f8v xf3 = *(const f8v*)(xb + 192 * 64);
    const f2v uf0 = *(const f2v*)(ub);
    const f2v uf1 = *(const f2v*)(ub + 64 * 16);
    const f2v uf2 = *(const f2v*)(ub + 128 * 16);
    const f2v uf3 = *(const f2v*)(ub + 192 * 16);

    // ---- stage phase-1 table (2320 float4) ----
    const float4* wsv = (const float4*)ws;
    float4* smv = (float4*)sm;
#pragma unroll
    for (int i = 0; i < 4; i++) smv[tid + i * BT] = wsv[tid + i * BT];
    if (tid < 2320 - 4 * BT) smv[tid + 4 * BT] = wsv[tid + 4 * BT];
    __syncthreads();

    // ---- pass 1: s = bv + C1 x + D12 u   (xf, uf die here) ----
    f8v s0 = lds8(sm + 9216 + c8);
    f8v s1 = s0, s2 = s0, s3 = s0;
    mv64_4(s0, s1, s2, s3, sm + 0,    c8, xf0, xf1, xf2, xf3, inLow, inHigh,
           std::make_integer_sequence<int, 64>{});
    mv16_4(s0, s1, s2, s3, sm + 8192, c8, uf0, uf1, uf2, uf3, inLow, inHigh,
           std::make_integer_sequence<int, 16>{});
    fence_sched();

    // ---- pass 2: substitution (pre-act) + deferred relu -> w ----
    subst_all4(s0, s1, s2, s3, sm + 4096, c8, inLow, inHigh,
               std::make_integer_sequence<int, 64>{});
    relu8(s0); relu8(s1); relu8(s2); relu8(s3);
    fence_sched();

    // ---- overlay: phase-2 table (live regs: s only) ----
    __syncthreads();
#pragma unroll
    for (int i = 0; i < 4; i++) smv[tid + i * BT] = wsv[2320 + tid + i * BT];
    if (tid < 2320 - 4 * BT) smv[tid + 4 * BT] = wsv[2320 + tid + 4 * BT];
    __syncthreads();
    // local layout now: AT@0 | B1T@4096 | B2T@8192 | bx@9216

    // ---- pass 3: acc = bx + B1 w   (s dies here) ----
    f8v acc0 = lds8(sm + 9216 + c8);
    f8v acc1 = acc0, acc2 = acc0, acc3 = acc0;
    mv64_4(acc0, acc1, acc2, acc3, sm + 4096, c8, s0, s1, s2, s3, inLow, inHigh,
           std::make_integer_sequence<int, 64>{});
    fence_sched();

    // ---- pass 4: reload x/u (L3-hot; laundered so pass-1 loads can't be
    //      CSE-forwarded and resurrect their live ranges), acc += Ax + B2u ----
    size_t r0 = row0;
    asm volatile("" : "+s"(r0));          // opaque: forces a true reload
    const float* xb2 = x + (r0 + oct) * 64 + c8;
    const float* ub2 = u + (r0 + oct) * 16 + (c << 1);
    const f8v xg0 = *(const f8v*)(xb2);
    const f8v xg1 = *(const f8v*)(xb2 + 64 * 64);
    const f8v xg2 = *(const f8v*)(xb2 + 128 * 64);
    const f8v xg3 = *(const f8v*)(xb2 + 192 * 64);
    const f2v ug0 = *(const f2v*)(ub2);
    const f2v ug1 = *(const f2v*)(ub2 + 64 * 16);
    const f2v ug2 = *(const f2v*)(ub2 + 128 * 16);
    const f2v ug3 = *(const f2v*)(ub2 + 192 * 16);
    mv64_4(acc0, acc1, acc2, acc3, sm + 0,    c8, xg0, xg1, xg2, xg3, inLow, inHigh,
           std::make_integer_sequence<int, 64>{});
    mv16_4(acc0, acc1, acc2, acc3, sm + 8192, c8, ug0, ug1, ug2, ug3, inLow, inHigh,
           std::make_integer_sequence<int, 16>{});

    // ---- four 32B stores: x_dot for the 4 rows ----
    float* ob = out + (row0 + oct) * 64 + c8;
    *(f8v*)(ob)            = acc0;
    *(f8v*)(ob + 64 * 64)  = acc1;
    *(f8v*)(ob + 128 * 64) = acc2;
    *(f8v*)(ob + 192 * 64) = acc3;
}

extern "C" void kernel_launch(void* const* d_in, const int* in_sizes, int n_in,
                              void* d_out, int out_size, void* d_ws, size_t ws_size,
                              hipStream_t stream) {
    const float* x   = (const float*)d_in[0];
    const float* u   = (const float*)d_in[1];
    const float* A   = (const float*)d_in[2];
    const float* B1  = (const float*)d_in[3];
    const float* B2  = (const float*)d_in[4];
    const float* C1  = (const float*)d_in[5];
    const float* D11 = (const float*)d_in[6];
    const float* D12 = (const float*)d_in[7];
    const float* bv  = (const float*)d_in[8];
    const float* bx  = (const float*)d_in[9];
    float* out = (float*)d_out;
    float* ws  = (float*)d_ws;

    prep_kernel<<<16, 256, 0, stream>>>(A, B1, B2, C1, D11, D12, bv, bx, ws);
    renl2_fused<<<NROWS / RPB, BT, 0, stream>>>(x, u, ws, out);
}

// Round 18
// 370.417 us; speedup vs baseline: 1.7205x; 1.7205x over previous
//
#include <hip/hip_runtime.h>
#include <utility>

// Problem constants: N=262144 rows, NX=NQ=64, NU=16, fp32.
#define NROWS 262144
#define BT 512                 // threads/block (8 waves)
#define RPB 256                // rows/block (= BT/4 quads * 2 rows each)

typedef float f16v __attribute__((ext_vector_type(16)));
typedef float f4v  __attribute__((ext_vector_type(4)));

// d_ws layout (floats) — two contiguous 9280-float phase blocks:
//  phase1 @0    : C1T[4096] | D11T[4096] | D12T[1024] | bv[64]
//  phase2 @9280 : AT [4096] | B1T [4096] | B2T [1024] | bx[64]
//  C1T[j*64+i]=C1[i][j]  D11T[i*64+k]=D11[k][i] (zeros at k<=i come from input)
//  D12T[j*64+i]=D12[i][j]  AT[j*64+k]=A[k][j]  B1T[i*64+k]=B1[k][i]
//  B2T[j*64+k]=B2[k][j]
// Fused kernel stages ONE 37.12 KB phase block at a time (overlay).
//
// r10 engine (131us, 52 VGPR, proven) + DUAL-PIPE m-stream:
// The binding resource is DS instruction throughput (~8.5 cyc/b128/CU:
// 32 waves x 1152 b128 = 131us, occupancy-invariant r7==r10). Dense-pass
// chunks alternate: even j from LDS, odd j from global ws (L1/L2-hot,
// identical data) — DS count 1152->704 (~80us), 448 loads ride the idle
// VMEM pipe. Substitution stays all-LDS (serial chain, latency-critical).
// R=4 is closed: four broadcast variants all failed on different resources
// (r11 DS-pipe, r12 tied-DPP, r15 reg-pressure, r17 DPP-temp spill).

__global__ void prep_kernel(const float* __restrict__ A, const float* __restrict__ B1,
                            const float* __restrict__ B2, const float* __restrict__ C1,
                            const float* __restrict__ D11, const float* __restrict__ D12,
                            const float* __restrict__ bv, const float* __restrict__ bx,
                            float* __restrict__ ws) {
    int g = blockIdx.x * 256 + threadIdx.x;
    if (g < 4096) {
        int r = g >> 6, c = g & 63;       // source row r, col c (64x64 row-major)
        int to = c * 64 + r;
        ws[0     + to] = C1[g];           // C1T
        ws[4096  + to] = D11[g];          // D11T
        ws[9280  + to] = A[g];            // AT
        ws[13376 + to] = B1[g];           // B1T
    }
    if (g < 1024) {
        int r = g >> 4, c = g & 15;       // 64x16 row-major source
        int to = c * 64 + r;
        ws[8192  + to] = D12[g];          // D12T
        ws[17472 + to] = B2[g];           // B2T
    }
    if (g < 64) {
        ws[9216  + g] = bv[g];
        ws[18496 + g] = bx[g];
    }
}

__device__ __forceinline__ f16v lds16(const float* p) { return *(const f16v*)p; }

// Pin pass boundaries (r6: +70 us): stops cross-pass live-range extension.
__device__ __forceinline__ void fence_sched() { __builtin_amdgcn_sched_barrier(0); }

// Quad-lane broadcast via DPP quad_perm:[Q,Q,Q,Q] — pure VALU (~2 cyc),
// single full-write op, no temps (the ONLY broadcast that never spilled).
template<int Q>
__device__ __forceinline__ float qbcast(float v) {
    return __int_as_float(__builtin_amdgcn_update_dpp(
        0, __float_as_int(v), Q * 0x55, 0xF, 0xF, true));
}

// Substitution step I, two rows sharing the D11T column — ALL-LDS.
// Deferred-relu form (r14-validated): s holds pre-activation throughout;
// D11T[I][I]==0 keeps the owner's element untouched, zeros at k<I are no-ops.
template<int I>
__device__ __forceinline__ void substep2(f16v& s0, f16v& s1, const float* D11s, int c16) {
    const float w0 = fmaxf(qbcast<(I >> 4)>(s0[I & 15]), 0.0f);
    const float w1 = fmaxf(qbcast<(I >> 4)>(s1[I & 15]), 0.0f);
    const f16v m = lds16(D11s + I * 64 + c16);
    s0 += m * w0;
    s1 += m * w1;
}
template<int... Is>
__device__ __forceinline__ void subst_all2(f16v& s0, f16v& s1, const float* D11s,
                                           int c16, std::integer_sequence<int, Is...>) {
    (substep2<Is>(s0, s1, D11s, c16), ...);
}

__device__ __forceinline__ void relu16(f16v& a) {
#pragma unroll
    for (int e = 0; e < 16; e++) a[e] = fmaxf(a[e], 0.0f);
}

// 64-dim matvec, two rows, dual-pipe m-stream: even J chunks from LDS
// (ds_read_b128 x4), odd J chunks from global ws (global_load_dwordx4 x4,
// L1/L2-hot, same values). Multipliers quad-distributed, DPP-broadcast.
template<int J>
__device__ __forceinline__ void mv64step2(f16v& a0, f16v& a1, const float* Ml,
                                          const float* Mg, int c16,
                                          const f16v& f0, const f16v& f1) {
    f16v m;
    if constexpr ((J & 1) == 0) m = lds16(Ml + J * 64 + c16);
    else                        m = *(const f16v*)(Mg + J * 64 + c16);
    a0 += m * qbcast<(J >> 4)>(f0[J & 15]);
    a1 += m * qbcast<(J >> 4)>(f1[J & 15]);
}
template<int... Js>
__device__ __forceinline__ void mv64_2(f16v& a0, f16v& a1, const float* Ml,
                                       const float* Mg, int c16,
                                       const f16v& f0, const f16v& f1,
                                       std::integer_sequence<int, Js...>) {
    (mv64step2<Js>(a0, a1, Ml, Mg, c16, f0, f1), ...);
}

// 16-dim matvec, two rows (u fragments: 4 floats/lane/row), same alternation.
template<int J>
__device__ __forceinline__ void mv16step2(f16v& a0, f16v& a1, const float* Ml,
                                          const float* Mg, int c16,
                                          const f4v& f0, const f4v& f1) {
    f16v m;
    if constexpr ((J & 1) == 0) m = lds16(Ml + J * 64 + c16);
    else                        m = *(const f16v*)(Mg + J * 64 + c16);
    a0 += m * qbcast<(J >> 2)>(f0[J & 3]);
    a1 += m * qbcast<(J >> 2)>(f1[J & 3]);
}
template<int... Js>
__device__ __forceinline__ void mv16_2(f16v& a0, f16v& a1, const float* Ml,
                                       const float* Mg, int c16,
                                       const f4v& f0, const f4v& f1,
                                       std::integer_sequence<int, Js...>) {
    (mv16step2<Js>(a0, a1, Ml, Mg, c16, f0, f1), ...);
}

// Fused kernel: quad (4 lanes) per TWO rows (row q and row q+128); each lane
// owns a 16-output chunk of each. ONE phase table LDS-resident at a time
// (overlay, 37.12 KB). launch_bounds(512,2): cap 128 — r7 proved 16 waves/CU
// performs identically when unit-bound, and the ~60-reg headroom is what the
// in-flight global m-chunks need (the r15 spill lesson).
// Pass order (r7/r10-proven liveness schedule):
//   stage p1; 1. s = bv + C1 x + D12 u  [xf, uf die]
//   2. substitution (all-LDS, pre-act); deferred relu -> w
//   overlay p2 (live: s only)
//   3. acc = bx + B1 w                  [s dies]
//   4. reload x,u; acc += Ax + B2u
__global__ __launch_bounds__(BT, 2) void renl2_fused(const float* __restrict__ x,
                                                     const float* __restrict__ u,
                                                     const float* __restrict__ ws,
                                                     float* __restrict__ out) {
    __shared__ __align__(64) float sm[9280];    // 37.12 KB
    const int tid = threadIdx.x;
    const int c16 = (tid & 3) << 4;       // quad chunk offset
    const size_t row0 = (size_t)blockIdx.x * RPB;   // rows [row0, row0+256)

    // ---- per-lane x/u fragments for both rows (fully coalesced) ----
    const f16v xf0 = *(const f16v*)(x + row0 * 64 + (size_t)tid * 16);
    const f16v xf1 = *(const f16v*)(x + (row0 + 128) * 64 + (size_t)tid * 16);
    const f4v  uf0 = *(const f4v*)(u + row0 * 16 + (size_t)tid * 4);
    const f4v  uf1 = *(const f4v*)(u + (row0 + 128) * 16 + (size_t)tid * 4);

    // ---- stage phase-1 table (2320 float4) ----
    const float4* wsv = (const float4*)ws;
    float4* smv = (float4*)sm;
#pragma unroll
    for (int i = 0; i < 4; i++) smv[tid + i * BT] = wsv[tid + i * BT];
    if (tid < 2320 - 4 * BT) smv[tid + 4 * BT] = wsv[tid + 4 * BT];
    __syncthreads();

    // ---- pass 1: s = bv + C1 x + D12 u   (xf, uf die here) ----
    f16v s0 = lds16(sm + 9216 + c16);
    f16v s1 = s0;
    mv64_2(s0, s1, sm + 0,    ws + 0,    c16, xf0, xf1,
           std::make_integer_sequence<int, 64>{});
    mv16_2(s0, s1, sm + 8192, ws + 8192, c16, uf0, uf1,
           std::make_integer_sequence<int, 16>{});
    fence_sched();

    // ---- pass 2: substitution (all-LDS) + deferred relu (s -> w) ----
    subst_all2(s0, s1, sm + 4096, c16, std::make_integer_sequence<int, 64>{});
    relu16(s0);
    relu16(s1);
    fence_sched();

    // ---- overlay: phase-2 table (live regs: s only) ----
    __syncthreads();
#pragma unroll
    for (int i = 0; i < 4; i++) smv[tid + i * BT] = wsv[2320 + tid + i * BT];
    if (tid < 2320 - 4 * BT) smv[tid + 4 * BT] = wsv[2320 + tid + 4 * BT];
    __syncthreads();
    // local layout now: AT@0 | B1T@4096 | B2T@8192 | bx@9216
    // global (ws) absolute: AT@9280 | B1T@13376 | B2T@17472

    // ---- pass 3: acc = bx + B1 w   (s dies here) ----
    f16v acc0 = lds16(sm + 9216 + c16);
    f16v acc1 = acc0;
    mv64_2(acc0, acc1, sm + 4096, ws + 13376, c16, s0, s1,
           std::make_integer_sequence<int, 64>{});
    fence_sched();

    // ---- pass 4: reload x/u (L3-hot; laundered so pass-1 loads can't be
    //      CSE-forwarded and resurrect their live ranges), acc += Ax + B2u ----
    size_t r0 = row0;
    asm volatile("" : "+s"(r0));          // opaque: forces a true reload
    const f16v xg0 = *(const f16v*)(x + r0 * 64 + (size_t)tid * 16);
    const f16v xg1 = *(const f16v*)(x + (r0 + 128) * 64 + (size_t)tid * 16);
    const f4v  ug0 = *(const f4v*)(u + r0 * 16 + (size_t)tid * 4);
    const f4v  ug1 = *(const f4v*)(u + (r0 + 128) * 16 + (size_t)tid * 4);
    mv64_2(acc0, acc1, sm + 0,    ws + 9280,  c16, xg0, xg1,
           std::make_integer_sequence<int, 64>{});
    mv16_2(acc0, acc1, sm + 8192, ws + 17472, c16, ug0, ug1,
           std::make_integer_sequence<int, 16>{});

    // ---- two 64B stores: x_dot for both rows ----
    const size_t q = (size_t)(tid >> 2);
    *(f16v*)(out + (row0 + q) * 64 + c16)       = acc0;
    *(f16v*)(out + (row0 + 128 + q) * 64 + c16) = acc1;
}

extern "C" void kernel_launch(void* const* d_in, const int* in_sizes, int n_in,
                              void* d_out, int out_size, void* d_ws, size_t ws_size,
                              hipStream_t stream) {
    const float* x   = (const float*)d_in[0];
    const float* u   = (const float*)d_in[1];
    const float* A   = (const float*)d_in[2];
    const float* B1  = (const float*)d_in[3];
    const float* B2  = (const float*)d_in[4];
    const float* C1  = (const float*)d_in[5];
    const float* D11 = (const float*)d_in[6];
    const float* D12 = (const float*)d_in[7];
    const float* bv  = (const float*)d_in[8];
    const float* bx  = (const float*)d_in[9];
    float* out = (float*)d_out;
    float* ws  = (float*)d_ws;

    prep_kernel<<<16, 256, 0, stream>>>(A, B1, B2, C1, D11, D12, bv, bx, ws);
    renl2_fused<<<NROWS / RPB, BT, 0, stream>>>(x, u, ws, out);
}